// Round 5
// baseline (339.602 us; speedup 1.0000x reference)
//
#include <hip/hip_runtime.h>
#include <stdint.h>

#define B_   16
#define S_   1024
#define N_   4096
#define C_   768
#define OUT_ 256
#define NT_  (C_ / 32)   // 24 k-tiles

typedef short bf16x8 __attribute__((ext_vector_type(8)));
typedef short bf16x4 __attribute__((ext_vector_type(4)));
typedef float f32x4  __attribute__((ext_vector_type(4)));

#define GLOBAL_AS __attribute__((address_space(1)))
#define LDS_AS    __attribute__((address_space(3)))

__device__ __forceinline__ unsigned short f2bf(float f) {
    unsigned int u = __float_as_uint(f);
    u += 0x7fffu + ((u >> 16) & 1u);   // round-to-nearest-even
    return (unsigned short)(u >> 16);
}

__device__ __forceinline__ void gl_lds16(const void* gsrc, void* ldst) {
    __builtin_amdgcn_global_load_lds((const GLOBAL_AS void*)gsrc,
                                     (LDS_AS void*)ldst, 16, 0, 0);
}

// ---------------------------------------------------------------------------
// K0: W fp32 -> bf16, vectorized 8 elem/thread. 96 blocks.
// ---------------------------------------------------------------------------
__global__ __launch_bounds__(256) void k_wconv(const float* __restrict__ W,
                                               unsigned short* __restrict__ Wb) {
    int i = (blockIdx.x * 256 + threadIdx.x) * 8;
    f32x4 a = *(const f32x4*)(W + i);
    f32x4 c = *(const f32x4*)(W + i + 4);
    bf16x8 o = {(short)f2bf(a[0]), (short)f2bf(a[1]),
                (short)f2bf(a[2]), (short)f2bf(a[3]),
                (short)f2bf(c[0]), (short)f2bf(c[1]),
                (short)f2bf(c[2]), (short)f2bf(c[3])};
    *(bf16x8*)(Wb + i) = o;
}

// ---------------------------------------------------------------------------
// K1: argmin_n d2(s,n).  Reference fp32 op order: ((s2 - 2*dot) + p2).
// UNCHANGED (numerics must match reference argmin exactly).
// ---------------------------------------------------------------------------
__global__ __launch_bounds__(256) void k_argmin(const float* __restrict__ seed,
                                                const float* __restrict__ pl,
                                                int* __restrict__ idx_out) {
    const int t    = threadIdx.x;
    const int lane = t & 63;
    const int w    = t >> 6;
    const int gw   = blockIdx.x * 4 + w;
    const int b    = gw >> 8;
    const int s0   = (gw & 255) * 4;

    float sx[4], sy[4], sz[4], s2[4], best[4];
    int   bidx[4];
#pragma unroll
    for (int j = 0; j < 4; ++j) {
        const float* sp = seed + (size_t)(b * S_ + s0 + j) * 3;
        sx[j] = sp[0]; sy[j] = sp[1]; sz[j] = sp[2];
        s2[j] = __fadd_rn(__fadd_rn(__fmul_rn(sx[j], sx[j]),
                                    __fmul_rn(sy[j], sy[j])),
                          __fmul_rn(sz[j], sz[j]));
        best[j] = 3.4e38f;
        bidx[j] = 0;
    }
    const float* pb = pl + (size_t)b * N_ * 3;

    for (int k = 0; k < N_ / 64; ++k) {
        const int   n  = k * 64 + lane;
        const float px = pb[n * 3 + 0];
        const float py = pb[n * 3 + 1];
        const float pz = pb[n * 3 + 2];
        const float p2 = __fadd_rn(__fadd_rn(__fmul_rn(px, px),
                                             __fmul_rn(py, py)),
                                   __fmul_rn(pz, pz));
#pragma unroll
        for (int j = 0; j < 4; ++j) {
            float dot = __fadd_rn(__fadd_rn(__fmul_rn(sx[j], px),
                                            __fmul_rn(sy[j], py)),
                                  __fmul_rn(sz[j], pz));
            float d2  = __fadd_rn(__fsub_rn(s2[j], __fmul_rn(2.0f, dot)), p2);
            if (d2 < best[j]) { best[j] = d2; bidx[j] = n; }
        }
    }

#pragma unroll
    for (int j = 0; j < 4; ++j) {
#pragma unroll
        for (int off = 32; off >= 1; off >>= 1) {
            float ob = __shfl_xor(best[j], off, 64);
            int   oi = __shfl_xor(bidx[j], off, 64);
            bool take = (ob < best[j]) || (ob == best[j] && oi < bidx[j]);
            if (take) { best[j] = ob; bidx[j] = oi; }
        }
        if (lane == 0) idx_out[b * S_ + s0 + j] = bidx[j];
    }
}

// ---------------------------------------------------------------------------
// K2 (ROUND 5 = R4 resubmit): P[b][n][o] = bf16( sum_c f[b][c][n]*Wb[o][c] ).
// m97-PURE staging: BOTH operands via global_load_lds (zero VALU, zero
// register round-trip, waves hit the barrier right after DMA issue).
// f staged RAW fp32 [32c][64n] (8 KB); conversion to bf16 moved into the
// compute phase (after barrier), where the VALU co-issues with MFMA.
// Tile 64n x 256o, 1024 blocks = 4 blocks/CU (independent barriers ->
// one block's drain hides under three blocks' compute: m97 mechanism).
// LDS 24 KB/block -> 96 KB/CU at 4 blocks. VGPR ~105 < 128 cap (256,4).
// ---------------------------------------------------------------------------
__global__ __launch_bounds__(256, 4) void k_pgemm(const float* __restrict__ f,
                                                  const unsigned short* __restrict__ Wb,
                                                  unsigned short* __restrict__ P) {
    __shared__ float          ldsF[32 * 64];    // [c][n] fp32, 8 KB (gl_lds linear)
    __shared__ unsigned short ldsW[256 * 32];   // [o][k] bf16, 16 KB (gl_lds linear)
    const int t    = threadIdx.x;
    const int b    = blockIdx.x >> 6;           // 16 b x 64 n-tiles
    const int nt   = blockIdx.x & 63;
    const int n0   = nt * 64;
    const int lane = t & 63;
    const int w    = t >> 6;                    // wave -> o-quarter (64 o)
    const int quad = lane >> 4, l16 = lane & 15;

    f32x4 acc[4][4];
#pragma unroll
    for (int i = 0; i < 4; ++i)
#pragma unroll
        for (int j = 0; j < 4; ++j) acc[i][j] = (f32x4){0.f, 0.f, 0.f, 0.f};

    // f DMA: call i stages c-rows [i*16, i*16+16) of the 32c x 64n fp32 tile.
    // thread -> (c = i*16 + t>>4, n-chunk = (t&15)*4); dst = i*4096 + t*16 B.
    const float* fSrc = f + (size_t)b * C_ * N_ + (size_t)(t >> 4) * N_ + n0 + (t & 15) * 4;
    // W DMA: call i stages o-rows [i*64, i*64+64); thread -> (o = i*64 + t>>2,
    // k-chunk = (t&3)*8); dst = i*4096 + t*16 B.
    const unsigned short* wSrc = Wb + (size_t)(t >> 2) * C_ + (t & 3) * 8;

    for (int kt = 0; kt < NT_; ++kt) {
        const int k0 = kt * 32;
        // stage f tile: 2 DMA issues (raw fp32, [c][n] layout preserved)
#pragma unroll
        for (int i = 0; i < 2; ++i)
            gl_lds16(fSrc + ((size_t)k0 + i * 16) * N_,
                     (char*)ldsF + i * 4096 + t * 16);
        // stage W tile: 4 DMA issues
#pragma unroll
        for (int i = 0; i < 4; ++i)
            gl_lds16(wSrc + (size_t)i * 64 * C_ + k0,
                     (char*)ldsW + i * 4096 + t * 16);
        __syncthreads();

        // A-frags: lane reads 8 fp32 (c = quad*8+j, n = mi*16+l16), cvt here
        bf16x8 aF[4];
        const float* lF = ldsF + quad * 8 * 64 + l16;
#pragma unroll
        for (int mi = 0; mi < 4; ++mi) {
            float tv[8];
#pragma unroll
            for (int j = 0; j < 8; ++j) tv[j] = lF[j * 64 + mi * 16];
            aF[mi] = (bf16x8){(short)f2bf(tv[0]), (short)f2bf(tv[1]),
                              (short)f2bf(tv[2]), (short)f2bf(tv[3]),
                              (short)f2bf(tv[4]), (short)f2bf(tv[5]),
                              (short)f2bf(tv[6]), (short)f2bf(tv[7])};
        }
#pragma unroll
        for (int oi = 0; oi < 4; ++oi) {
            bf16x8 bF = *(const bf16x8*)(ldsW + (w * 64 + oi * 16 + l16) * 32 + quad * 8);
#pragma unroll
            for (int mi = 0; mi < 4; ++mi)
                acc[mi][oi] = __builtin_amdgcn_mfma_f32_16x16x32_bf16(
                    aF[mi], bF, acc[mi][oi], 0, 0, 0);
        }
        __syncthreads();
    }

    // epilogue: D row = n (A side), col = o (B side); store bf16
    unsigned short* Pb = P + ((size_t)b * N_ + n0) * OUT_;
#pragma unroll
    for (int mi = 0; mi < 4; ++mi) {
#pragma unroll
        for (int r = 0; r < 4; ++r) {
            const int n = mi * 16 + quad * 4 + r;
            unsigned short* row = Pb + (size_t)n * OUT_;
#pragma unroll
            for (int oi = 0; oi < 4; ++oi) {
                const int o = w * 64 + oi * 16 + l16;
                row[o] = f2bf(acc[mi][oi][r]);
            }
        }
    }
}

// ---------------------------------------------------------------------------
// K3: out[b][o][s] = f32(P[b][idx[b][s]][o]) + bias[o]   (UNCHANGED)
// ---------------------------------------------------------------------------
__global__ __launch_bounds__(256) void k_out(const unsigned short* __restrict__ P,
                                             const int* __restrict__ idx,
                                             const float* __restrict__ bias,
                                             float* __restrict__ out) {
    __shared__ unsigned short tl[64 * 260];
    const int t  = threadIdx.x;
    const int b  = blockIdx.x >> 4;
    const int st = blockIdx.x & 15;
    const int s0 = st * 64;
    const unsigned short* Pb = P + (size_t)b * N_ * OUT_;

#pragma unroll
    for (int i = 0; i < 8; ++i) {
        const int g = i * 256 + t;
        const int s = g >> 5;            // 0..63
        const int p = g & 31;            // 16B chunk within 512B row
        const int n = idx[b * S_ + s0 + s];
        const unsigned short* src = Pb + (size_t)n * OUT_ + p * 8;
        uint2 u0 = *(const uint2*)src;
        uint2 u1 = *(const uint2*)(src + 4);
        *(uint2*)(tl + s * 260 + p * 8)     = u0;   // b64 writes (8B aligned)
        *(uint2*)(tl + s * 260 + p * 8 + 4) = u1;
    }
    __syncthreads();

    const int lane = t & 63;
    const int w    = t >> 6;
    float* ob = out + (size_t)b * OUT_ * S_ + s0;
#pragma unroll 4
    for (int oo = 0; oo < 64; ++oo) {
        const int o = w * 64 + oo;
        const unsigned short u = tl[lane * 260 + o];
        const float val = __uint_as_float(((unsigned int)u) << 16) + bias[o];
        ob[(size_t)o * S_ + lane] = val;
    }
}

// ---------------------------------------------------------------------------
// Workspace: [0,64K) idx int32[16][1024]
//            [64K,64K+384K) Wb bf16[256][768]
//            [512K, 512K+33.6MB) P bf16[16][4096][256]
// ---------------------------------------------------------------------------
extern "C" void kernel_launch(void* const* d_in, const int* in_sizes, int n_in,
                              void* d_out, int out_size, void* d_ws, size_t ws_size,
                              hipStream_t stream) {
    const float* seed = (const float*)d_in[0];   // [16,1024,3]
    const float* pl   = (const float*)d_in[1];   // [16,4096,3]
    const float* f    = (const float*)d_in[2];   // [16,768,4096]
    const float* W    = (const float*)d_in[3];   // [256,768]
    const float* bias = (const float*)d_in[4];   // [256]
    float* out = (float*)d_out;                  // [16,256,1024] fp32

    int* idx            = (int*)d_ws;
    unsigned short* Wb  = (unsigned short*)((char*)d_ws + 65536);
    unsigned short* P   = (unsigned short*)((char*)d_ws + 524288);

    k_wconv <<<96,   256, 0, stream>>>(W, Wb);
    k_argmin<<<1024, 256, 0, stream>>>(seed, pl, idx);
    k_pgemm <<<1024, 256, 0, stream>>>(f, Wb, P);
    k_out   <<<256,  256, 0, stream>>>(P, idx, bias, out);
}

// Round 7
// 331.830 us; speedup vs baseline: 1.0234x; 1.0234x over previous
//
#include <hip/hip_runtime.h>
#include <stdint.h>

#define B_   16
#define S_   1024
#define N_   4096
#define C_   768
#define OUT_ 256
#define NT_  (C_ / 32)   // 24 k-tiles

typedef short bf16x8 __attribute__((ext_vector_type(8)));
typedef short bf16x4 __attribute__((ext_vector_type(4)));
typedef float f32x4  __attribute__((ext_vector_type(4)));

#define GLOBAL_AS __attribute__((address_space(1)))
#define LDS_AS    __attribute__((address_space(3)))

__device__ __forceinline__ unsigned short f2bf(float f) {
    unsigned int u = __float_as_uint(f);
    u += 0x7fffu + ((u >> 16) & 1u);   // round-to-nearest-even
    return (unsigned short)(u >> 16);
}

__device__ __forceinline__ void gl_lds16(const void* gsrc, void* ldst) {
    __builtin_amdgcn_global_load_lds((const GLOBAL_AS void*)gsrc,
                                     (LDS_AS void*)ldst, 16, 0, 0);
}

// ---------------------------------------------------------------------------
// K0: W fp32 -> bf16, vectorized 8 elem/thread. 96 blocks.
// ---------------------------------------------------------------------------
__global__ __launch_bounds__(256) void k_wconv(const float* __restrict__ W,
                                               unsigned short* __restrict__ Wb) {
    int i = (blockIdx.x * 256 + threadIdx.x) * 8;
    f32x4 a = *(const f32x4*)(W + i);
    f32x4 c = *(const f32x4*)(W + i + 4);
    bf16x8 o = {(short)f2bf(a[0]), (short)f2bf(a[1]),
                (short)f2bf(a[2]), (short)f2bf(a[3]),
                (short)f2bf(c[0]), (short)f2bf(c[1]),
                (short)f2bf(c[2]), (short)f2bf(c[3])};
    *(bf16x8*)(Wb + i) = o;
}

// ---------------------------------------------------------------------------
// K1 (ROUND 7): argmin + pgemm fused SEQUENTIALLY in one ordinary kernel.
// No data dependency between the phases -> no grid sync needed; k_out
// (separate dispatch) sees idx and P across the kernel boundary.
// Purpose: (a) the combined dispatch (~115-125 us) exceeds the ~118 us
// harness fills -> finally visible in rocprof top-5 with real counters;
// (b) removes one launch gap; (c) block stagger overlaps late argmin
// with early pgemm staging.
//
// Phase 1: argmin_n d2(s,n), reference fp32 op order ((s2 - 2*dot) + p2),
//          byte-identical numerics to the passing R0/R3 kernels.
// Phase 2: pgemm P[b][n][o] = bf16(sum_c f[b][c][n] * Wb[o][c]),
//          64n x 256o tile (bid = b*64 + nt), BK=32, R3 body:
//          f reg-staged with packed-pair b32 transpose writes into
//          [n][k] rows of 36 shorts (reads <=2-way by bank arithmetic);
//          W via linear global_load_lds (b128 reads bank-uniform).
// LDS 20.5 KB -> 4 blocks/CU under __launch_bounds__(256,4).
// ---------------------------------------------------------------------------
__global__ __launch_bounds__(256, 4) void k_fused2(const float* __restrict__ seed,
                                                   const float* __restrict__ pl,
                                                   int* __restrict__ idx_out,
                                                   const float* __restrict__ f,
                                                   const unsigned short* __restrict__ Wb,
                                                   unsigned short* __restrict__ P) {
    __shared__ unsigned short ldsF[64 * 36];    // [n][k], row pad 36 (72 B), 4.5 KB
    __shared__ unsigned short ldsW[256 * 32];   // [o][k], linear (gl_lds), 16 KB
    const int bid  = blockIdx.x;
    const int t    = threadIdx.x;
    const int lane = t & 63;
    const int w    = t >> 6;

    // ========================= Phase 1: argmin =========================
    {
        const int gw = bid * 4 + w;
        const int b  = gw >> 8;
        const int s0 = (gw & 255) * 4;

        float sx[4], sy[4], sz[4], s2[4], best[4];
        int   bidx[4];
#pragma unroll
        for (int j = 0; j < 4; ++j) {
            const float* sp = seed + (size_t)(b * S_ + s0 + j) * 3;
            sx[j] = sp[0]; sy[j] = sp[1]; sz[j] = sp[2];
            s2[j] = __fadd_rn(__fadd_rn(__fmul_rn(sx[j], sx[j]),
                                        __fmul_rn(sy[j], sy[j])),
                              __fmul_rn(sz[j], sz[j]));
            best[j] = 3.4e38f;
            bidx[j] = 0;
        }
        const float* pb = pl + (size_t)b * N_ * 3;

        for (int k = 0; k < N_ / 64; ++k) {
            const int   n  = k * 64 + lane;
            const float px = pb[n * 3 + 0];
            const float py = pb[n * 3 + 1];
            const float pz = pb[n * 3 + 2];
            const float p2 = __fadd_rn(__fadd_rn(__fmul_rn(px, px),
                                                 __fmul_rn(py, py)),
                                       __fmul_rn(pz, pz));
#pragma unroll
            for (int j = 0; j < 4; ++j) {
                float dot = __fadd_rn(__fadd_rn(__fmul_rn(sx[j], px),
                                                __fmul_rn(sy[j], py)),
                                      __fmul_rn(sz[j], pz));
                float d2  = __fadd_rn(__fsub_rn(s2[j], __fmul_rn(2.0f, dot)), p2);
                if (d2 < best[j]) { best[j] = d2; bidx[j] = n; }
            }
        }

#pragma unroll
        for (int j = 0; j < 4; ++j) {
#pragma unroll
            for (int off = 32; off >= 1; off >>= 1) {
                float ob = __shfl_xor(best[j], off, 64);
                int   oi = __shfl_xor(bidx[j], off, 64);
                bool take = (ob < best[j]) || (ob == best[j] && oi < bidx[j]);
                if (take) { best[j] = ob; bidx[j] = oi; }
            }
            if (lane == 0) idx_out[b * S_ + s0 + j] = bidx[j];
        }
    }

    // ========================= Phase 2: pgemm ==========================
    {
        const int b    = bid >> 6;           // 16 b x 64 n-tiles
        const int nt   = bid & 63;
        const int n0   = nt * 64;
        const int quad = lane >> 4, l16 = lane & 15;

        f32x4 acc[4][4];
#pragma unroll
        for (int i = 0; i < 4; ++i)
#pragma unroll
            for (int j = 0; j < 4; ++j) acc[i][j] = (f32x4){0.f, 0.f, 0.f, 0.f};

        // f staging: thread owns 2 c-rows x 4 n (packed-pair b32 writes)
        const int cb = t >> 4;            // 0..15 -> k = k0 + cb*2 + {0,1}
        const int nb = t & 15;            // 0..15 -> n = n0 + nb*4 + {0..3}
        const float* fB = f + (size_t)b * C_ * N_ + n0 + nb * 4;
        const unsigned short* wSrc = Wb + (size_t)(t >> 2) * C_ + (t & 3) * 8;

        for (int kt = 0; kt < NT_; ++kt) {
            const int k0 = kt * 32;
            // stage W: 256 rows x 32 k, 4 DMA issues (dst = uniform + t*16B)
#pragma unroll
            for (int i = 0; i < 4; ++i)
                gl_lds16(wSrc + (size_t)i * 64 * C_ + k0, ldsW + i * 2048 + t * 8);
            // stage f-tile 32c x 64n
            f32x4 v0 = *(const f32x4*)(fB + (size_t)(k0 + cb * 2 + 0) * N_);
            f32x4 v1 = *(const f32x4*)(fB + (size_t)(k0 + cb * 2 + 1) * N_);
#pragma unroll
            for (int i = 0; i < 4; ++i) {
                unsigned int pk = (unsigned int)f2bf(v0[i]) |
                                  ((unsigned int)f2bf(v1[i]) << 16);
                *(unsigned int*)(ldsF + (nb * 4 + i) * 36 + cb * 2) = pk;
            }
            __syncthreads();

            bf16x8 aF[4];
#pragma unroll
            for (int mi = 0; mi < 4; ++mi) {
                const unsigned short* p = ldsF + (mi * 16 + l16) * 36 + quad * 8;
                bf16x4 lo = *(const bf16x4*)p;
                bf16x4 hi = *(const bf16x4*)(p + 4);
                aF[mi] = __builtin_shufflevector(lo, hi, 0, 1, 2, 3, 4, 5, 6, 7);
            }
#pragma unroll
            for (int oi = 0; oi < 4; ++oi) {
                bf16x8 bF = *(const bf16x8*)(ldsW + (w * 64 + oi * 16 + l16) * 32 + quad * 8);
#pragma unroll
                for (int mi = 0; mi < 4; ++mi)
                    acc[mi][oi] = __builtin_amdgcn_mfma_f32_16x16x32_bf16(
                        aF[mi], bF, acc[mi][oi], 0, 0, 0);
            }
            __syncthreads();
        }

        // epilogue: D row = n (A side), col = o (B side); store bf16
        unsigned short* Pb = P + ((size_t)b * N_ + n0) * OUT_;
#pragma unroll
        for (int mi = 0; mi < 4; ++mi) {
#pragma unroll
            for (int r = 0; r < 4; ++r) {
                const int n = mi * 16 + quad * 4 + r;
                unsigned short* row = Pb + (size_t)n * OUT_;
#pragma unroll
                for (int oi = 0; oi < 4; ++oi) {
                    const int o = w * 64 + oi * 16 + l16;
                    row[o] = f2bf(acc[mi][oi][r]);
                }
            }
        }
    }
}

// ---------------------------------------------------------------------------
// K3 (ROUND 7): out[b][o][s] = f32(P[b][idx[b][s]][o]) + bias[o]
// 4x finer split than before: 1024 blocks = (b, s-tile of 64, o-quarter of 64).
// Gather 64s x 64o slice -> LDS [64][68] -> transposed coalesced stores.
// ---------------------------------------------------------------------------
__global__ __launch_bounds__(256) void k_out(const unsigned short* __restrict__ P,
                                             const int* __restrict__ idx,
                                             const float* __restrict__ bias,
                                             float* __restrict__ out) {
    __shared__ unsigned short tl[64 * 68];
    const int t  = threadIdx.x;
    const int b  = blockIdx.x >> 6;     // 16 b
    const int st = (blockIdx.x >> 2) & 15;  // 16 s-tiles of 64
    const int oq = blockIdx.x & 3;      // 4 o-quarters of 64
    const int s0 = st * 64;
    const unsigned short* Pb = P + (size_t)b * N_ * OUT_;

#pragma unroll
    for (int i = 0; i < 2; ++i) {
        const int g = i * 256 + t;
        const int s = g >> 3;           // 0..63
        const int p = g & 7;            // 16B chunk within the 128B o-slice
        const int n = idx[b * S_ + s0 + s];
        const unsigned short* src = Pb + (size_t)n * OUT_ + oq * 64 + p * 8;
        uint2 u0 = *(const uint2*)src;
        uint2 u1 = *(const uint2*)(src + 4);
        *(uint2*)(tl + s * 68 + p * 8)     = u0;   // 8B writes, 8B aligned
        *(uint2*)(tl + s * 68 + p * 8 + 4) = u1;
    }
    __syncthreads();

    const int lane = t & 63;
    const int w    = t >> 6;
    float* ob = out + (size_t)b * OUT_ * S_ + s0;
#pragma unroll 4
    for (int oo = 0; oo < 16; ++oo) {
        const int col = w * 16 + oo;            // 0..63 within quarter
        const int o   = oq * 64 + col;
        const unsigned short u = tl[lane * 68 + col];
        const float val = __uint_as_float(((unsigned int)u) << 16) + bias[o];
        ob[(size_t)o * S_ + lane] = val;        // 64 consecutive s: 256B coalesced
    }
}

// ---------------------------------------------------------------------------
// Workspace: [0,64K) idx int32[16][1024]
//            [64K,64K+384K) Wb bf16[256][768]
//            [512K, 512K+33.6MB) P bf16[16][4096][256]
// ---------------------------------------------------------------------------
extern "C" void kernel_launch(void* const* d_in, const int* in_sizes, int n_in,
                              void* d_out, int out_size, void* d_ws, size_t ws_size,
                              hipStream_t stream) {
    const float* seed = (const float*)d_in[0];   // [16,1024,3]
    const float* pl   = (const float*)d_in[1];   // [16,4096,3]
    const float* f    = (const float*)d_in[2];   // [16,768,4096]
    const float* W    = (const float*)d_in[3];   // [256,768]
    const float* bias = (const float*)d_in[4];   // [256]
    float* out = (float*)d_out;                  // [16,256,1024] fp32

    int* idx            = (int*)d_ws;
    unsigned short* Wb  = (unsigned short*)((char*)d_ws + 65536);
    unsigned short* P   = (unsigned short*)((char*)d_ws + 524288);

    k_wconv <<<96,   256, 0, stream>>>(W, Wb);
    k_fused2<<<1024, 256, 0, stream>>>(seed, pl, idx, f, Wb, P);
    k_out   <<<1024, 256, 0, stream>>>(P, idx, bias, out);
}